// Round 6
// baseline (299.085 us; speedup 1.0000x reference)
//
#include <hip/hip_runtime.h>
#include <hip/hip_cooperative_groups.h>

namespace cg = cooperative_groups;

#define BB 16
#define NN 25200
#define NC 80
#define ROWL 85
#define KTOP 4096
#define MAXDET 1000
#define CONF_T 0.55f
#define IOU_T 0.45f
#define MAX_WH_F 7680.0f
#define CNT_STRIDE 32    // per-image counters 128 B apart
#define PCNT_STRIDE 16   // per-(image,class) counters 64 B apart
#define CCAP 256         // per-class candidate cap (mean ~44, sd ~6.6 -> 30+ sigma)
#define SEGS 394         // ceil(NN/64)

// ws layout (bytes):
//   pcnt   : [0,      81920)   16*80*16 u32  per-(b,c) bucket counters
//   cnt    : [81920,  83968)   16*32 u32     per-image candidate count
//   kcnt   : [83968,  86016)   16*32 u32     per-image kept count
//   buckets: [86016,  2707456) 16*80*256 u64 per-(b,c) candidate keys
//   kept   : [2707456,3231744) 16*4096 u64   per-image kept pool
#define OFF_CNT   81920
#define OFF_KCNT  83968
#define OFF_BUCK  86016
#define OFF_KEPT  2707456
#define ZERO_WORDS 21504

#define NBLK 512
#define NTHR 256
#define NWAVE (NBLK * NTHR / 64)   // 2048 waves

// ================= single cooperative kernel: all 4 phases =================
__global__ __launch_bounds__(NTHR, 2) void fused_all(
    const float* __restrict__ pred, const int* __restrict__ ihp,
    const int* __restrict__ iwp, float* __restrict__ out,
    unsigned int* __restrict__ pcnt, unsigned int* __restrict__ cnt,
    unsigned int* __restrict__ kcnt,
    unsigned long long* __restrict__ buckets,
    unsigned long long* __restrict__ kept) {
  cg::grid_group grid = cg::this_grid();
  const int tid = threadIdx.x;
  const int lane = tid & 63;
  const int gwave = blockIdx.x * (NTHR / 64) + (tid >> 6);

  // ---- P0: zero counters (pcnt,cnt,kcnt contiguous from ws base) ----
  for (int i = blockIdx.x * NTHR + tid; i < ZERO_WORDS; i += NBLK * NTHR)
    pcnt[i] = 0u;
  grid.sync();

  // ---- P1: wave-cooperative score + bucket scatter (2 candidates/iter) ----
  for (int ch = gwave; ch < BB * SEGS; ch += NWAVE) {
    const int b = ch / SEGS;
    const int a0 = (ch - b * SEGS) * 64;
    const float* __restrict__ pb = pred + (size_t)b * NN * ROWL;
    const int a = a0 + lane;
    float obj = 0.0f;
    if (a < NN) obj = pb[(size_t)a * ROWL + 4];
    unsigned long long mask = __ballot(obj > CONF_T);
    bool valid = false;
    unsigned long long key = 0ull;
    while (mask) {
      int s0 = __ffsll(mask) - 1; mask &= mask - 1;
      int s1 = -1;
      if (mask) { s1 = __ffsll(mask) - 1; mask &= mask - 1; }
      const int sB = (s1 >= 0) ? s1 : s0;
      const float* rowA = pb + (size_t)(a0 + s0) * ROWL;
      const float* rowB = pb + (size_t)(a0 + sB) * ROWL;
      float objA = __shfl(obj, s0, 64);
      float objB = __shfl(obj, sB, 64);
      float bvA = rowA[5 + lane] * objA; int biA = lane;   // product then max: ref fp order
      float bvB = rowB[5 + lane] * objB; int biB = lane;
      if (lane < 16) {
        float vA = rowA[69 + lane] * objA;
        if (vA > bvA) { bvA = vA; biA = 64 + lane; }       // strict > : first-index argmax
        float vB = rowB[69 + lane] * objB;
        if (vB > bvB) { bvB = vB; biB = 64 + lane; }
      }
      #pragma unroll
      for (int off = 32; off >= 1; off >>= 1) {            // two independent chains (ILP)
        float ovA = __shfl_xor(bvA, off, 64); int oiA = __shfl_xor(biA, off, 64);
        if (ovA > bvA || (ovA == bvA && oiA < biA)) { bvA = ovA; biA = oiA; }
        float ovB = __shfl_xor(bvB, off, 64); int oiB = __shfl_xor(biB, off, 64);
        if (ovB > bvB || (ovB == bvB && oiB < biB)) { bvB = ovB; biB = oiB; }
      }
      if (lane == s0 && bvA > CONF_T) {
        valid = true;
        // key: score bits | ~anchor (lower anchor first = lax.top_k tie order) | cls
        key = ((unsigned long long)__float_as_uint(bvA) << 32) |
              ((unsigned long long)((~(unsigned)(a0 + s0)) & 0xFFFFu) << 16) |
              (unsigned long long)(unsigned)biA;
      }
      if (s1 >= 0 && lane == s1 && bvB > CONF_T) {
        valid = true;
        key = ((unsigned long long)__float_as_uint(bvB) << 32) |
              ((unsigned long long)((~(unsigned)(a0 + s1)) & 0xFFFFu) << 16) |
              (unsigned long long)(unsigned)biB;
      }
    }
    if (valid) {
      int c = (int)(key & 0xFFFFu);
      unsigned int slot = atomicAdd(&pcnt[(b * NC + c) * PCNT_STRIDE], 1u);
      if (slot < CCAP)
        buckets[((size_t)(b * NC + c) << 8) + slot] = key;  // order arbitrary; sorted later
    }
    unsigned long long vm = __ballot(valid);
    if (lane == 0 && vm)
      atomicAdd(&cnt[b * CNT_STRIDE], (unsigned int)__popcll(vm));
  }
  grid.sync();

  // ---- P2: per-(image,class) in-register sort + greedy NMS ----
  // Cross-class IoU exactly 0 (cls*7680 offset) -> per-class greedy == ref global scan.
  for (int pcid = gwave; pcid < BB * NC; pcid += NWAVE) {
    const int b = pcid / NC;
    const int c = pcid - b * NC;
    unsigned int pc = pcnt[(b * NC + c) * PCNT_STRIDE];
    int n_c = (int)(pc < (unsigned)CCAP ? pc : (unsigned)CCAP);
    const unsigned long long* __restrict__ bk = buckets + ((size_t)(b * NC + c) << 8);
    unsigned long long v[4];
    #pragma unroll
    for (int r = 0; r < 4; ++r) {
      int e = (r << 6) + lane;
      v[r] = (e < n_c) ? bk[e] : 0ull;   // slots >= n_c may hold stale data: guard
    }
    int count = (int)cnt[b * CNT_STRIDE];
    if (count > KTOP) {
      // dead path statistically (count ~3400+-55 vs 4096): image-wide 4096th-key
      // threshold via bitwise binary search over all buckets.
      unsigned long long T = 0ull;
      for (int bit = 63; bit >= 0; --bit) {
        unsigned long long T2 = T | (1ull << bit);
        int cge = 0;
        for (int c2 = 0; c2 < NC; ++c2) {
          unsigned int p2 = pcnt[(b * NC + c2) * PCNT_STRIDE];
          int n2 = (int)(p2 < (unsigned)CCAP ? p2 : (unsigned)CCAP);
          const unsigned long long* bk2 = buckets + ((size_t)(b * NC + c2) << 8);
          for (int base2 = 0; base2 < n2; base2 += 64) {
            int i = base2 + lane;
            bool ge = (i < n2) && (bk2[i] >= T2);
            cge += (int)__popcll(__ballot(ge));
          }
        }
        if (cge >= KTOP) T = T2;   // keys unique -> exactly KTOP keys >= final T
      }
      #pragma unroll
      for (int r = 0; r < 4; ++r) if (v[r] < T) v[r] = 0ull;
      n_c = 0;
      #pragma unroll
      for (int r = 0; r < 4; ++r) n_c += (int)__popcll(__ballot(v[r] != 0ull));
    }
    if (n_c == 0) continue;

    // in-register wave bitonic sort of 256 (4/lane), descending; pads (0) sink
    for (int k2 = 2; k2 <= 256; k2 <<= 1) {
      if (k2 == 256) {
        #pragma unroll
        for (int r = 0; r < 2; ++r) {
          unsigned e = (unsigned)((r << 6) + lane);
          bool desc = ((e & k2) == 0);
          unsigned long long lo_ = v[r], hi_ = v[r + 2];
          bool sw = desc ? (lo_ < hi_) : (lo_ > hi_);
          v[r] = sw ? hi_ : lo_; v[r + 2] = sw ? lo_ : hi_;
        }
      }
      if (k2 >= 128) {
        #pragma unroll
        for (int rr = 0; rr < 2; ++rr) {
          int r = rr * 2;
          unsigned e = (unsigned)((r << 6) + lane);
          bool desc = ((e & k2) == 0);
          unsigned long long lo_ = v[r], hi_ = v[r + 1];
          bool sw = desc ? (lo_ < hi_) : (lo_ > hi_);
          v[r] = sw ? hi_ : lo_; v[r + 1] = sw ? lo_ : hi_;
        }
      }
      int j0 = (k2 >> 1) < 32 ? (k2 >> 1) : 32;
      for (int j = j0; j >= 1; j >>= 1) {
        #pragma unroll
        for (int r = 0; r < 4; ++r) {
          unsigned e = (unsigned)((r << 6) + lane);
          unsigned long long vo = __shfl_xor(v[r], j, 64);
          bool desc = ((e & k2) == 0);
          bool low = ((e & j) == 0);
          if ((desc == low) ? (vo > v[r]) : (vo < v[r])) v[r] = vo;
        }
      }
    }

    // gather offset boxes (exact reference op order)
    const float* __restrict__ pb = pred + (size_t)b * NN * ROWL;
    float x1r[4], y1r[4], x2r[4], y2r[4], ar[4];
    int keepr[4];
    const float offc = (float)c * MAX_WH_F;
    #pragma unroll
    for (int r = 0; r < 4; ++r) {
      int e = (r << 6) + lane;
      keepr[r] = 0; x1r[r] = 0.f; y1r[r] = 0.f; x2r[r] = 0.f; y2r[r] = 0.f; ar[r] = 0.f;
      if (e < n_c) {
        unsigned int lo = (unsigned int)v[r];
        int aa = (int)((~(lo >> 16)) & 0xFFFFu);
        const float* row = pb + (size_t)aa * ROWL;
        float cx = row[0], cy = row[1], w2 = row[2], h2 = row[3];
        float x1 = (cx - w2 / 2.0f) + offc;
        float y1 = (cy - h2 / 2.0f) + offc;
        float x2 = (cx + w2 / 2.0f) + offc;
        float y2 = (cy + h2 / 2.0f) + offc;
        x1r[r] = x1; y1r[r] = y1; x2r[r] = x2; y2r[r] = y2;
        ar[r] = (x2 - x1) * (y2 - y1);
        keepr[r] = 1;
      }
    }

    // greedy NMS, wave-local (shfl broadcasts, no barriers)
    for (int i2 = 0; i2 < n_c; ++i2) {
      int ci = i2 >> 6, li = i2 & 63;
      int ki; float bx1v, by1v, bx2v, by2v, bav;
      #define BCAST(R) { ki = __shfl(keepr[R], li, 64); bx1v = __shfl(x1r[R], li, 64); \
                         by1v = __shfl(y1r[R], li, 64); bx2v = __shfl(x2r[R], li, 64); \
                         by2v = __shfl(y2r[R], li, 64); bav = __shfl(ar[R], li, 64); }
      switch (ci) {  // wave-uniform
        case 0: BCAST(0); break;
        case 1: BCAST(1); break;
        case 2: BCAST(2); break;
        default: BCAST(3); break;
      }
      #undef BCAST
      if (!ki) continue;
      #pragma unroll
      for (int r = 0; r < 4; ++r) {
        int e = (r << 6) + lane;
        if (keepr[r] && e > i2) {
          float ltx = fmaxf(bx1v, x1r[r]), lty = fmaxf(by1v, y1r[r]);
          float rbx = fminf(bx2v, x2r[r]), rby = fminf(by2v, y2r[r]);
          float wv = rbx - ltx; wv = wv > 0.0f ? wv : 0.0f;
          float hv = rby - lty; hv = hv > 0.0f ? hv : 0.0f;
          float inter = wv * hv;
          float iou = inter / (bav + ar[r] - inter + 1e-7f);
          if (iou > IOU_T) keepr[r] = 0;
        }
      }
    }

    // append kept keys to per-image pool (one aggregated atomic per wave)
    unsigned long long m[4];
    int tot = 0;
    #pragma unroll
    for (int r = 0; r < 4; ++r) {
      m[r] = __ballot(keepr[r] != 0);
      tot += (int)__popcll(m[r]);
    }
    unsigned int base3 = 0;
    if (lane == 0) base3 = atomicAdd(&kcnt[b * CNT_STRIDE], (unsigned int)tot);
    base3 = (unsigned int)__shfl((int)base3, 0, 64);
    unsigned int start = base3;
    #pragma unroll
    for (int r = 0; r < 4; ++r) {
      if (keepr[r]) {
        unsigned int slot = start + (unsigned int)__popcll(m[r] & ((1ull << lane) - 1ull));
        if (slot < (unsigned)KTOP) kept[(size_t)b * KTOP + slot] = v[r];
      }
      start += (unsigned int)__popcll(m[r]);
    }
  }
  grid.sync();

  // ---- P3: rank kept keys (= #larger keys; unique keys -> exact top_k order), output ----
  const int h = ihp[0], w3 = iwp[0];
  const double gd = fmin(640.0 / (double)h, 640.0 / (double)w3);
  const float gain = (float)gd;
  const float padx = (float)((640.0 - (double)w3 * gd) * 0.5);
  const float pady = (float)((640.0 - (double)h * gd) * 0.5);
  const float wf = (float)w3, hf = (float)h;
  for (int ch = gwave; ch < BB * (KTOP / 64); ch += NWAVE) {
    const int b = ch >> 6;
    const int i0 = (ch & 63) << 6;
    const int i = i0 + lane;
    unsigned int kcr = kcnt[b * CNT_STRIDE];
    const int kc = (int)(kcr < (unsigned)KTOP ? kcr : (unsigned)KTOP);
    const unsigned long long* __restrict__ kb = kept + (size_t)b * KTOP;
    if (i0 < kc) {   // wave-uniform: some lane ranks
      unsigned long long q = (i < kc) ? kb[i] : 0ull;
      int rank = 0;
      int u = 0;
      for (; u + 8 <= kc; u += 8) {   // uniform-address broadcast loads
        #pragma unroll
        for (int t = 0; t < 8; ++t) rank += (kb[u + t] > q) ? 1 : 0;
      }
      for (; u < kc; ++u) rank += (kb[u] > q) ? 1 : 0;
      if (i < kc && rank < MAXDET) {
        unsigned int lo = (unsigned int)q;
        int aa = (int)((~(lo >> 16)) & 0xFFFFu);
        int cls = (int)(lo & 0xFFFFu);
        float score = __uint_as_float((unsigned int)(q >> 32));
        const float* row = pred + ((size_t)b * NN + aa) * ROWL;
        float cx = row[0], cy = row[1], wd = row[2], ht = row[3];
        float x1 = cx - wd / 2.0f, y1 = cy - ht / 2.0f;
        float x2 = cx + wd / 2.0f, y2 = cy + ht / 2.0f;
        x1 = rintf(fminf(fmaxf((x1 - padx) / gain, 0.0f), wf));
        y1 = rintf(fminf(fmaxf((y1 - pady) / gain, 0.0f), hf));
        x2 = rintf(fminf(fmaxf((x2 - padx) / gain, 0.0f), wf));
        y2 = rintf(fminf(fmaxf((y2 - pady) / gain, 0.0f), hf));
        float* o = out + ((size_t)b * MAXDET + rank) * 6;
        o[0] = x1; o[1] = y1; o[2] = x2; o[3] = y2;
        o[4] = score; o[5] = (float)cls;
      }
    }
    if (i >= kc && i < MAXDET) {   // rows [kc, MAXDET): zero-fill
      float* o = out + ((size_t)b * MAXDET + i) * 6;
      o[0] = 0.0f; o[1] = 0.0f; o[2] = 0.0f; o[3] = 0.0f; o[4] = 0.0f; o[5] = 0.0f;
    }
  }
}

// ================= fallback path: round-4 kernels (identical results) =================
__global__ void zero_kernel(unsigned int* __restrict__ w) {
  w[blockIdx.x * 256 + threadIdx.x] = 0u;
}

__global__ __launch_bounds__(256) void score_kernel(const float* __restrict__ pred,
                             unsigned long long* __restrict__ buckets,
                             unsigned int* __restrict__ pcnt,
                             unsigned int* __restrict__ cnt) {
  const int b = blockIdx.y;
  const int lane = threadIdx.x & 63;
  const int a0 = blockIdx.x * 256 + (threadIdx.x & ~63);
  const int a = a0 + lane;
  const float* __restrict__ pb = pred + (size_t)b * NN * ROWL;
  float obj = 0.0f;
  if (a < NN) obj = pb[(size_t)a * ROWL + 4];
  unsigned long long mask = __ballot(obj > CONF_T);
  bool valid = false;
  unsigned long long key = 0ull;
  while (mask) {
    int s = __ffsll(mask) - 1;
    mask &= mask - 1;
    int aa = a0 + s;
    const float* row = pb + (size_t)aa * ROWL;
    float objs = __shfl(obj, s, 64);
    float bv = row[5 + lane] * objs;
    int bi = lane;
    if (lane < 16) {
      float v2 = row[69 + lane] * objs;
      if (v2 > bv) { bv = v2; bi = 64 + lane; }
    }
    #pragma unroll
    for (int off = 32; off >= 1; off >>= 1) {
      float ov = __shfl_xor(bv, off, 64);
      int oi = __shfl_xor(bi, off, 64);
      if (ov > bv || (ov == bv && oi < bi)) { bv = ov; bi = oi; }
    }
    if (lane == s && bv > CONF_T) {
      valid = true;
      key = ((unsigned long long)__float_as_uint(bv) << 32) |
            ((unsigned long long)((~(unsigned)aa) & 0xFFFFu) << 16) |
            (unsigned long long)(unsigned)bi;
    }
  }
  if (valid) {
    int c = (int)(key & 0xFFFFu);
    unsigned int slot = atomicAdd(&pcnt[(b * NC + c) * PCNT_STRIDE], 1u);
    if (slot < CCAP)
      buckets[((size_t)(b * NC + c) << 8) + slot] = key;
  }
  unsigned long long vm = __ballot(valid);
  int nv = __popcll(vm);
  if (lane == 0 && nv)
    atomicAdd(&cnt[b * CNT_STRIDE], (unsigned int)nv);
}

__global__ __launch_bounds__(64) void class_nms_kernel(
    const float* __restrict__ pred,
    const unsigned long long* __restrict__ buckets,
    const unsigned int* __restrict__ pcnt,
    const unsigned int* __restrict__ cnt,
    unsigned long long* __restrict__ kept,
    unsigned int* __restrict__ kcnt) {
  const int c = blockIdx.x;
  const int b = blockIdx.y;
  const int lane = threadIdx.x;
  unsigned int pc = pcnt[(b * NC + c) * PCNT_STRIDE];
  int n_c = (int)(pc < (unsigned)CCAP ? pc : (unsigned)CCAP);
  const unsigned long long* __restrict__ bk = buckets + ((size_t)(b * NC + c) << 8);
  unsigned long long v[4];
  #pragma unroll
  for (int r = 0; r < 4; ++r) {
    int e = (r << 6) + lane;
    v[r] = (e < n_c) ? bk[e] : 0ull;
  }
  int count = (int)cnt[b * CNT_STRIDE];
  if (count > KTOP) {
    unsigned long long T = 0ull;
    for (int bit = 63; bit >= 0; --bit) {
      unsigned long long T2 = T | (1ull << bit);
      int cge = 0;
      for (int c2 = 0; c2 < NC; ++c2) {
        unsigned int p2 = pcnt[(b * NC + c2) * PCNT_STRIDE];
        int n2 = (int)(p2 < (unsigned)CCAP ? p2 : (unsigned)CCAP);
        const unsigned long long* bk2 = buckets + ((size_t)(b * NC + c2) << 8);
        for (int base2 = 0; base2 < n2; base2 += 64) {
          int i = base2 + lane;
          bool ge = (i < n2) && (bk2[i] >= T2);
          cge += (int)__popcll(__ballot(ge));
        }
      }
      if (cge >= KTOP) T = T2;
    }
    #pragma unroll
    for (int r = 0; r < 4; ++r) if (v[r] < T) v[r] = 0ull;
    n_c = 0;
    #pragma unroll
    for (int r = 0; r < 4; ++r) n_c += (int)__popcll(__ballot(v[r] != 0ull));
  }
  if (n_c == 0) return;
  for (int k2 = 2; k2 <= 256; k2 <<= 1) {
    if (k2 == 256) {
      #pragma unroll
      for (int r = 0; r < 2; ++r) {
        unsigned e = (unsigned)((r << 6) + lane);
        bool desc = ((e & k2) == 0);
        unsigned long long lo_ = v[r], hi_ = v[r + 2];
        bool sw = desc ? (lo_ < hi_) : (lo_ > hi_);
        v[r] = sw ? hi_ : lo_; v[r + 2] = sw ? lo_ : hi_;
      }
    }
    if (k2 >= 128) {
      #pragma unroll
      for (int rr = 0; rr < 2; ++rr) {
        int r = rr * 2;
        unsigned e = (unsigned)((r << 6) + lane);
        bool desc = ((e & k2) == 0);
        unsigned long long lo_ = v[r], hi_ = v[r + 1];
        bool sw = desc ? (lo_ < hi_) : (lo_ > hi_);
        v[r] = sw ? hi_ : lo_; v[r + 1] = sw ? lo_ : hi_;
      }
    }
    int j0 = (k2 >> 1) < 32 ? (k2 >> 1) : 32;
    for (int j = j0; j >= 1; j >>= 1) {
      #pragma unroll
      for (int r = 0; r < 4; ++r) {
        unsigned e = (unsigned)((r << 6) + lane);
        unsigned long long vo = __shfl_xor(v[r], j, 64);
        bool desc = ((e & k2) == 0);
        bool low = ((e & j) == 0);
        if ((desc == low) ? (vo > v[r]) : (vo < v[r])) v[r] = vo;
      }
    }
  }
  const float* __restrict__ pb = pred + (size_t)b * NN * ROWL;
  float x1r[4], y1r[4], x2r[4], y2r[4], ar[4];
  int keepr[4];
  const float offc = (float)c * MAX_WH_F;
  #pragma unroll
  for (int r = 0; r < 4; ++r) {
    int e = (r << 6) + lane;
    keepr[r] = 0; x1r[r] = 0.f; y1r[r] = 0.f; x2r[r] = 0.f; y2r[r] = 0.f; ar[r] = 0.f;
    if (e < n_c) {
      unsigned int lo = (unsigned int)v[r];
      int aa = (int)((~(lo >> 16)) & 0xFFFFu);
      const float* row = pb + (size_t)aa * ROWL;
      float cx = row[0], cy = row[1], w2 = row[2], h2 = row[3];
      float x1 = (cx - w2 / 2.0f) + offc;
      float y1 = (cy - h2 / 2.0f) + offc;
      float x2 = (cx + w2 / 2.0f) + offc;
      float y2 = (cy + h2 / 2.0f) + offc;
      x1r[r] = x1; y1r[r] = y1; x2r[r] = x2; y2r[r] = y2;
      ar[r] = (x2 - x1) * (y2 - y1);
      keepr[r] = 1;
    }
  }
  for (int i2 = 0; i2 < n_c; ++i2) {
    int ci = i2 >> 6, li = i2 & 63;
    int ki; float bx1v, by1v, bx2v, by2v, bav;
    #define BCAST(R) { ki = __shfl(keepr[R], li, 64); bx1v = __shfl(x1r[R], li, 64); \
                       by1v = __shfl(y1r[R], li, 64); bx2v = __shfl(x2r[R], li, 64); \
                       by2v = __shfl(y2r[R], li, 64); bav = __shfl(ar[R], li, 64); }
    switch (ci) {
      case 0: BCAST(0); break;
      case 1: BCAST(1); break;
      case 2: BCAST(2); break;
      default: BCAST(3); break;
    }
    #undef BCAST
    if (!ki) continue;
    #pragma unroll
    for (int r = 0; r < 4; ++r) {
      int e = (r << 6) + lane;
      if (keepr[r] && e > i2) {
        float ltx = fmaxf(bx1v, x1r[r]), lty = fmaxf(by1v, y1r[r]);
        float rbx = fminf(bx2v, x2r[r]), rby = fminf(by2v, y2r[r]);
        float wv = rbx - ltx; wv = wv > 0.0f ? wv : 0.0f;
        float hv = rby - lty; hv = hv > 0.0f ? hv : 0.0f;
        float inter = wv * hv;
        float iou = inter / (bav + ar[r] - inter + 1e-7f);
        if (iou > IOU_T) keepr[r] = 0;
      }
    }
  }
  unsigned long long m[4];
  int tot = 0;
  #pragma unroll
  for (int r = 0; r < 4; ++r) {
    m[r] = __ballot(keepr[r] != 0);
    tot += (int)__popcll(m[r]);
  }
  unsigned int base3 = 0;
  if (lane == 0) base3 = atomicAdd(&kcnt[b * CNT_STRIDE], (unsigned int)tot);
  base3 = (unsigned int)__shfl((int)base3, 0, 64);
  unsigned int start = base3;
  #pragma unroll
  for (int r = 0; r < 4; ++r) {
    if (keepr[r]) {
      unsigned int slot = start + (unsigned int)__popcll(m[r] & ((1ull << lane) - 1ull));
      if (slot < (unsigned)KTOP) kept[(size_t)b * KTOP + slot] = v[r];
    }
    start += (unsigned int)__popcll(m[r]);
  }
}

__global__ __launch_bounds__(256) void out_kernel(
    const float* __restrict__ pred,
    const unsigned long long* __restrict__ kept,
    const unsigned int* __restrict__ kcnt,
    const int* __restrict__ ihp, const int* __restrict__ iwp,
    float* __restrict__ out) {
  const int b = blockIdx.y;
  const int i = blockIdx.x * 256 + threadIdx.x;
  unsigned int kcr = kcnt[b * CNT_STRIDE];
  const int kc = (int)(kcr < (unsigned)KTOP ? kcr : (unsigned)KTOP);
  __shared__ unsigned long long tile[256];
  const unsigned long long* __restrict__ kb = kept + (size_t)b * KTOP;
  unsigned long long q = 0ull;
  const bool havq = (i < kc);
  if (havq) q = kb[i];
  int rank = 0;
  const int nt = (kc + 255) >> 8;
  for (int t = 0; t < nt; ++t) {
    int j = t * 256 + threadIdx.x;
    __syncthreads();
    tile[threadIdx.x] = (j < kc) ? kb[j] : 0ull;
    __syncthreads();
    if (havq) {
      int lim = kc - t * 256; if (lim > 256) lim = 256;
      if (lim == 256) {
        #pragma unroll 8
        for (int u = 0; u < 256; ++u) rank += (tile[u] > q) ? 1 : 0;
      } else {
        for (int u = 0; u < lim; ++u) rank += (tile[u] > q) ? 1 : 0;
      }
    }
  }
  int h = ihp[0], w3 = iwp[0];
  double gd = fmin(640.0 / (double)h, 640.0 / (double)w3);
  float gain = (float)gd;
  float padx = (float)((640.0 - (double)w3 * gd) * 0.5);
  float pady = (float)((640.0 - (double)h * gd) * 0.5);
  float wf = (float)w3, hf = (float)h;
  if (havq) {
    if (rank < MAXDET) {
      unsigned int lo = (unsigned int)q;
      int aa = (int)((~(lo >> 16)) & 0xFFFFu);
      int cls = (int)(lo & 0xFFFFu);
      float score = __uint_as_float((unsigned int)(q >> 32));
      const float* row = pred + ((size_t)b * NN + aa) * ROWL;
      float cx = row[0], cy = row[1], wd = row[2], ht = row[3];
      float x1 = cx - wd / 2.0f, y1 = cy - ht / 2.0f;
      float x2 = cx + wd / 2.0f, y2 = cy + ht / 2.0f;
      x1 = rintf(fminf(fmaxf((x1 - padx) / gain, 0.0f), wf));
      y1 = rintf(fminf(fmaxf((y1 - pady) / gain, 0.0f), hf));
      x2 = rintf(fminf(fmaxf((x2 - padx) / gain, 0.0f), wf));
      y2 = rintf(fminf(fmaxf((y2 - pady) / gain, 0.0f), hf));
      float* o = out + ((size_t)b * MAXDET + rank) * 6;
      o[0] = x1; o[1] = y1; o[2] = x2; o[3] = y2;
      o[4] = score; o[5] = (float)cls;
    }
  } else if (i < MAXDET) {
    float* o = out + ((size_t)b * MAXDET + i) * 6;
    o[0] = 0.0f; o[1] = 0.0f; o[2] = 0.0f; o[3] = 0.0f; o[4] = 0.0f; o[5] = 0.0f;
  }
}

extern "C" void kernel_launch(void* const* d_in, const int* in_sizes, int n_in,
                              void* d_out, int out_size, void* d_ws, size_t ws_size,
                              hipStream_t stream) {
  const float* pred = (const float*)d_in[0];
  const int* ih = (const int*)d_in[1];
  const int* iw = (const int*)d_in[2];
  float* out = (float*)d_out;
  char* ws = (char*)d_ws;

  unsigned int* pcnt = (unsigned int*)ws;
  unsigned int* cnt = (unsigned int*)(ws + OFF_CNT);
  unsigned int* kcnt = (unsigned int*)(ws + OFF_KCNT);
  unsigned long long* buckets = (unsigned long long*)(ws + OFF_BUCK);
  unsigned long long* kept = (unsigned long long*)(ws + OFF_KEPT);

  void* args[] = {(void*)&pred, (void*)&ih, (void*)&iw, (void*)&out,
                  (void*)&pcnt, (void*)&cnt, (void*)&kcnt,
                  (void*)&buckets, (void*)&kept};
  hipError_t e = hipLaunchCooperativeKernel((const void*)fused_all,
                                            dim3(NBLK), dim3(NTHR),
                                            args, 0, stream);
  if (e != hipSuccess) {
    // fallback: round-4 four-kernel path (bit-identical results)
    zero_kernel<<<ZERO_WORDS / 256, 256, 0, stream>>>((unsigned int*)ws);
    dim3 sgrid((NN + 255) / 256, BB);
    score_kernel<<<sgrid, 256, 0, stream>>>(pred, buckets, pcnt, cnt);
    dim3 cgrid(NC, BB);
    class_nms_kernel<<<cgrid, 64, 0, stream>>>(pred, buckets, pcnt, cnt, kept, kcnt);
    dim3 ogrid(KTOP / 256, BB);
    out_kernel<<<ogrid, 256, 0, stream>>>(pred, kept, kcnt, ih, iw, out);
  }
}

// Round 7
// 120.034 us; speedup vs baseline: 2.4917x; 2.4917x over previous
//
#include <hip/hip_runtime.h>

#define BB 16
#define NN 25200
#define NC 80
#define ROWL 85
#define KTOP 4096
#define MAXDET 1000
#define CONF_T 0.55f
#define IOU_T 0.45f
#define MAX_WH_F 7680.0f
#define CNT_STRIDE 32    // per-image counters 128 B apart
#define PCNT_STRIDE 16   // per-(image,class) counters 64 B apart
#define CCAP 256         // per-class candidate cap (mean ~44, sd ~6.6 -> 30+ sigma)

// ws layout (bytes):
//   pcnt   : [0,      81920)   16*80*16 u32  per-(b,c) bucket counters
//   cnt    : [81920,  83968)   16*32 u32     per-image candidate count
//   kcnt   : [83968,  86016)   16*32 u32     per-image kept count
//   buckets: [86016,  2707456) 16*80*256 u64 per-(b,c) candidate keys
//   kept   : [2707456,3231744) 16*4096 u64   per-image kept pool
#define OFF_CNT   81920
#define OFF_KCNT  83968
#define OFF_BUCK  86016
#define OFF_KEPT  2707456
#define ZERO_WORDS 21504

__global__ void zero_kernel(unsigned int* __restrict__ w) {
  w[blockIdx.x * 256 + threadIdx.x] = 0u;
}

// ---------------- Kernel A: wave-coop score, fmax tree + ballot-argmax ----------------
// Serial chain per candidate: 6 shfl-fmax steps (was 12 shfl + cmp/sel), two
// candidates in flight per iteration (independent chains -> ILP 2).
__global__ __launch_bounds__(256) void score_kernel(const float* __restrict__ pred,
                             unsigned long long* __restrict__ buckets,
                             unsigned int* __restrict__ pcnt,
                             unsigned int* __restrict__ cnt) {
  const int b = blockIdx.y;
  const int lane = threadIdx.x & 63;
  const int a0 = blockIdx.x * 256 + (threadIdx.x & ~63);
  const int a = a0 + lane;
  const float* __restrict__ pb = pred + (size_t)b * NN * ROWL;
  float obj = 0.0f;
  if (a < NN) obj = pb[(size_t)a * ROWL + 4];
  unsigned long long mask = __ballot(obj > CONF_T);
  bool valid = false;
  unsigned long long key = 0ull;
  while (mask) {
    int s0 = __ffsll(mask) - 1; mask &= mask - 1;
    int s1 = -1;
    if (mask) { s1 = __ffsll(mask) - 1; mask &= mask - 1; }
    const int sB = (s1 >= 0) ? s1 : s0;
    const float* rowA = pb + (size_t)(a0 + s0) * ROWL;
    const float* rowB = pb + (size_t)(a0 + sB) * ROWL;
    float objA = __shfl(obj, s0, 64);
    float objB = __shfl(obj, sB, 64);
    // products in reference fp order (cls*obj then max); neutral -1 < any product (>=0)
    float pA0 = rowA[5 + lane] * objA;
    float pB0 = rowB[5 + lane] * objB;
    float pA1 = (lane < 16) ? rowA[69 + lane] * objA : -1.0f;
    float pB1 = (lane < 16) ? rowB[69 + lane] * objB : -1.0f;
    float mA = fmaxf(pA0, pA1);
    float mB = fmaxf(pB0, pB1);
    #pragma unroll
    for (int off = 32; off >= 1; off >>= 1) {   // two independent chains (ILP)
      mA = fmaxf(mA, __shfl_xor(mA, off, 64));
      mB = fmaxf(mB, __shfl_xor(mB, off, 64));
    }
    // first-index argmax via ballot: fmaxf returns an input bitwise, so == is exact
    unsigned long long eA0 = __ballot(pA0 == mA);
    unsigned long long eA1 = __ballot(pA1 == mA);  // lanes>=16 hold -1.0f: can't equal mA>=0
    unsigned long long eB0 = __ballot(pB0 == mB);
    unsigned long long eB1 = __ballot(pB1 == mB);
    int iA0 = eA0 ? (__ffsll(eA0) - 1) : 1000;
    int iA1 = eA1 ? (63 + __ffsll(eA1)) : 1000;   // 64 + (ffs-1)
    int biA = iA0 < iA1 ? iA0 : iA1;
    int iB0 = eB0 ? (__ffsll(eB0) - 1) : 1000;
    int iB1 = eB1 ? (63 + __ffsll(eB1)) : 1000;
    int biB = iB0 < iB1 ? iB0 : iB1;
    if (lane == s0 && mA > CONF_T) {
      valid = true;
      // key: score bits | ~anchor (lower anchor first = lax.top_k tie order) | cls
      key = ((unsigned long long)__float_as_uint(mA) << 32) |
            ((unsigned long long)((~(unsigned)(a0 + s0)) & 0xFFFFu) << 16) |
            (unsigned long long)(unsigned)biA;
    }
    if (s1 >= 0 && lane == s1 && mB > CONF_T) {
      valid = true;
      key = ((unsigned long long)__float_as_uint(mB) << 32) |
            ((unsigned long long)((~(unsigned)(a0 + s1)) & 0xFFFFu) << 16) |
            (unsigned long long)(unsigned)biB;
    }
  }
  if (valid) {
    int c = (int)(key & 0xFFFFu);
    unsigned int slot = atomicAdd(&pcnt[(b * NC + c) * PCNT_STRIDE], 1u);
    if (slot < CCAP)
      buckets[((size_t)(b * NC + c) << 8) + slot] = key;  // order arbitrary; sorted later
  }
  unsigned long long vm = __ballot(valid);
  if (lane == 0 && vm)
    atomicAdd(&cnt[b * CNT_STRIDE], (unsigned int)__popcll(vm));
}

// IoU suppress helper (exact reference arithmetic)
__device__ __forceinline__ bool iou_sup(float ax1, float ay1, float ax2, float ay2,
                                        float aar, float bx1, float by1, float bx2,
                                        float by2, float bar) {
  float ltx = fmaxf(ax1, bx1), lty = fmaxf(ay1, by1);
  float rbx = fminf(ax2, bx2), rby = fminf(ay2, by2);
  float wv = rbx - ltx; wv = wv > 0.0f ? wv : 0.0f;
  float hv = rby - lty; hv = hv > 0.0f ? hv : 0.0f;
  float inter = wv * hv;
  float iou = inter / (aar + bar - inter + 1e-7f);
  return iou > IOU_T;
}

// ---------------- Kernel B: per-(image,class) sort + NMS ----------------
// 1280 independent 1-wave blocks. Cross-class IoU exactly 0 (cls*7680 offset)
// -> per-class greedy in per-class score order == reference's global scan.
// Fast path n_c<=64 (>=99.8% of buckets): 1-register sort + 1-register NMS.
__global__ __launch_bounds__(64) void class_nms_kernel(
    const float* __restrict__ pred,
    const unsigned long long* __restrict__ buckets,
    const unsigned int* __restrict__ pcnt,
    const unsigned int* __restrict__ cnt,
    unsigned long long* __restrict__ kept,
    unsigned int* __restrict__ kcnt) {
  const int c = blockIdx.x;
  const int b = blockIdx.y;
  const int lane = threadIdx.x;
  unsigned int pc = pcnt[(b * NC + c) * PCNT_STRIDE];
  int n_c = (int)(pc < (unsigned)CCAP ? pc : (unsigned)CCAP);
  const unsigned long long* __restrict__ bk = buckets + ((size_t)(b * NC + c) << 8);
  const float* __restrict__ pb = pred + (size_t)b * NN * ROWL;
  const float offc = (float)c * MAX_WH_F;
  const int count = (int)cnt[b * CNT_STRIDE];

  if (n_c == 0) return;

  if (n_c <= 64 && count <= KTOP) {
    // ======== fast path: everything in one register ========
    unsigned long long v0 = (lane < n_c) ? bk[lane] : 0ull;
    // 64-elem bitonic, descending (pads 0 sink)
    for (int k2 = 2; k2 <= 64; k2 <<= 1) {
      for (int j = k2 >> 1; j >= 1; j >>= 1) {
        unsigned long long vo = __shfl_xor(v0, j, 64);
        bool desc = ((lane & k2) == 0);
        bool low = ((lane & j) == 0);
        if ((desc == low) ? (vo > v0) : (vo < v0)) v0 = vo;
      }
    }
    // gather offset box (exact reference op order)
    float x1 = 0.f, y1 = 0.f, x2 = 0.f, y2 = 0.f, aar = 0.f;
    int keep0 = 0;
    if (lane < n_c) {
      unsigned int lo = (unsigned int)v0;
      int aa = (int)((~(lo >> 16)) & 0xFFFFu);
      const float* row = pb + (size_t)aa * ROWL;
      float cx = row[0], cy = row[1], w2 = row[2], h2 = row[3];
      x1 = (cx - w2 / 2.0f) + offc;
      y1 = (cy - h2 / 2.0f) + offc;
      x2 = (cx + w2 / 2.0f) + offc;
      y2 = (cy + h2 / 2.0f) + offc;
      aar = (x2 - x1) * (y2 - y1);
      keep0 = 1;
    }
    for (int i2 = 0; i2 < n_c; ++i2) {
      int ki = __shfl(keep0, i2, 64);
      float bx1 = __shfl(x1, i2, 64), by1 = __shfl(y1, i2, 64);
      float bx2 = __shfl(x2, i2, 64), by2 = __shfl(y2, i2, 64);
      float bar = __shfl(aar, i2, 64);
      if (!ki) continue;
      if (keep0 && lane > i2 &&
          iou_sup(bx1, by1, bx2, by2, bar, x1, y1, x2, y2, aar))
        keep0 = 0;
    }
    unsigned long long m0 = __ballot(keep0 != 0);
    int tot = (int)__popcll(m0);
    unsigned int base3 = 0;
    if (lane == 0) base3 = atomicAdd(&kcnt[b * CNT_STRIDE], (unsigned int)tot);
    base3 = (unsigned int)__shfl((int)base3, 0, 64);
    if (keep0) {
      unsigned int slot = base3 + (unsigned int)__popcll(m0 & ((1ull << lane) - 1ull));
      if (slot < (unsigned)KTOP) kept[(size_t)b * KTOP + slot] = v0;
    }
    return;
  }

  // ======== slow path (n_c>64 or count>KTOP): round-4 verbatim ========
  unsigned long long v[4];
  #pragma unroll
  for (int r = 0; r < 4; ++r) {
    int e = (r << 6) + lane;
    v[r] = (e < n_c) ? bk[e] : 0ull;   // slots >= n_c may hold stale data: guard
  }
  if (count > KTOP) {
    // dead path statistically (count ~3400+-55 vs 4096): image-wide 4096th-key
    // threshold via bitwise binary search over all buckets.
    unsigned long long T = 0ull;
    for (int bit = 63; bit >= 0; --bit) {
      unsigned long long T2 = T | (1ull << bit);
      int cge = 0;
      for (int c2 = 0; c2 < NC; ++c2) {
        unsigned int p2 = pcnt[(b * NC + c2) * PCNT_STRIDE];
        int n2 = (int)(p2 < (unsigned)CCAP ? p2 : (unsigned)CCAP);
        const unsigned long long* bk2 = buckets + ((size_t)(b * NC + c2) << 8);
        for (int base2 = 0; base2 < n2; base2 += 64) {
          int i = base2 + lane;
          bool ge = (i < n2) && (bk2[i] >= T2);
          cge += (int)__popcll(__ballot(ge));
        }
      }
      if (cge >= KTOP) T = T2;   // keys unique -> exactly KTOP keys >= final T
    }
    #pragma unroll
    for (int r = 0; r < 4; ++r) if (v[r] < T) v[r] = 0ull;
    n_c = 0;
    #pragma unroll
    for (int r = 0; r < 4; ++r) n_c += (int)__popcll(__ballot(v[r] != 0ull));
    if (n_c == 0) return;
  }
  for (int k2 = 2; k2 <= 256; k2 <<= 1) {
    if (k2 == 256) {
      #pragma unroll
      for (int r = 0; r < 2; ++r) {
        unsigned e = (unsigned)((r << 6) + lane);
        bool desc = ((e & k2) == 0);
        unsigned long long lo_ = v[r], hi_ = v[r + 2];
        bool sw = desc ? (lo_ < hi_) : (lo_ > hi_);
        v[r] = sw ? hi_ : lo_; v[r + 2] = sw ? lo_ : hi_;
      }
    }
    if (k2 >= 128) {
      #pragma unroll
      for (int rr = 0; rr < 2; ++rr) {
        int r = rr * 2;
        unsigned e = (unsigned)((r << 6) + lane);
        bool desc = ((e & k2) == 0);
        unsigned long long lo_ = v[r], hi_ = v[r + 1];
        bool sw = desc ? (lo_ < hi_) : (lo_ > hi_);
        v[r] = sw ? hi_ : lo_; v[r + 1] = sw ? lo_ : hi_;
      }
    }
    int j0 = (k2 >> 1) < 32 ? (k2 >> 1) : 32;
    for (int j = j0; j >= 1; j >>= 1) {
      #pragma unroll
      for (int r = 0; r < 4; ++r) {
        unsigned e = (unsigned)((r << 6) + lane);
        unsigned long long vo = __shfl_xor(v[r], j, 64);
        bool desc = ((e & k2) == 0);
        bool low = ((e & j) == 0);
        if ((desc == low) ? (vo > v[r]) : (vo < v[r])) v[r] = vo;
      }
    }
  }
  float x1r[4], y1r[4], x2r[4], y2r[4], ar[4];
  int keepr[4];
  #pragma unroll
  for (int r = 0; r < 4; ++r) {
    int e = (r << 6) + lane;
    keepr[r] = 0; x1r[r] = 0.f; y1r[r] = 0.f; x2r[r] = 0.f; y2r[r] = 0.f; ar[r] = 0.f;
    if (e < n_c) {
      unsigned int lo = (unsigned int)v[r];
      int aa = (int)((~(lo >> 16)) & 0xFFFFu);
      const float* row = pb + (size_t)aa * ROWL;
      float cx = row[0], cy = row[1], w2 = row[2], h2 = row[3];
      x1r[r] = (cx - w2 / 2.0f) + offc;
      y1r[r] = (cy - h2 / 2.0f) + offc;
      x2r[r] = (cx + w2 / 2.0f) + offc;
      y2r[r] = (cy + h2 / 2.0f) + offc;
      ar[r] = (x2r[r] - x1r[r]) * (y2r[r] - y1r[r]);
      keepr[r] = 1;
    }
  }
  for (int i2 = 0; i2 < n_c; ++i2) {
    int ci = i2 >> 6, li = i2 & 63;
    int ki; float bx1v, by1v, bx2v, by2v, bav;
    #define BCAST(R) { ki = __shfl(keepr[R], li, 64); bx1v = __shfl(x1r[R], li, 64); \
                       by1v = __shfl(y1r[R], li, 64); bx2v = __shfl(x2r[R], li, 64); \
                       by2v = __shfl(y2r[R], li, 64); bav = __shfl(ar[R], li, 64); }
    switch (ci) {  // wave-uniform
      case 0: BCAST(0); break;
      case 1: BCAST(1); break;
      case 2: BCAST(2); break;
      default: BCAST(3); break;
    }
    #undef BCAST
    if (!ki) continue;
    #pragma unroll
    for (int r = 0; r < 4; ++r) {
      int e = (r << 6) + lane;
      if (keepr[r] && e > i2 &&
          iou_sup(bx1v, by1v, bx2v, by2v, bav, x1r[r], y1r[r], x2r[r], y2r[r], ar[r]))
        keepr[r] = 0;
    }
  }
  unsigned long long m[4];
  int tot = 0;
  #pragma unroll
  for (int r = 0; r < 4; ++r) {
    m[r] = __ballot(keepr[r] != 0);
    tot += (int)__popcll(m[r]);
  }
  unsigned int base3 = 0;
  if (lane == 0) base3 = atomicAdd(&kcnt[b * CNT_STRIDE], (unsigned int)tot);
  base3 = (unsigned int)__shfl((int)base3, 0, 64);
  unsigned int start = base3;
  #pragma unroll
  for (int r = 0; r < 4; ++r) {
    if (keepr[r]) {
      unsigned int slot = start + (unsigned int)__popcll(m[r] & ((1ull << lane) - 1ull));
      if (slot < (unsigned)KTOP) kept[(size_t)b * KTOP + slot] = v[r];
    }
    start += (unsigned int)__popcll(m[r]);
  }
}

// ---------------- Kernel C: rank kept keys, transform, write output ----------------
// Final position of a kept key = #{kept keys of this image with larger key}
// (keys unique; key order == score desc, anchor asc == reference top_k order).
__global__ __launch_bounds__(256) void out_kernel(
    const float* __restrict__ pred,
    const unsigned long long* __restrict__ kept,
    const unsigned int* __restrict__ kcnt,
    const int* __restrict__ ihp, const int* __restrict__ iwp,
    float* __restrict__ out) {
  const int b = blockIdx.y;
  const int i = blockIdx.x * 256 + threadIdx.x;
  unsigned int kcr = kcnt[b * CNT_STRIDE];
  const int kc = (int)(kcr < (unsigned)KTOP ? kcr : (unsigned)KTOP);
  __shared__ unsigned long long tile[256];
  const unsigned long long* __restrict__ kb = kept + (size_t)b * KTOP;
  unsigned long long q = 0ull;
  const bool havq = (i < kc);
  if (havq) q = kb[i];
  int rank = 0;
  const int nt = (kc + 255) >> 8;
  for (int t = 0; t < nt; ++t) {
    int j = t * 256 + threadIdx.x;
    __syncthreads();
    tile[threadIdx.x] = (j < kc) ? kb[j] : 0ull;
    __syncthreads();
    if (havq) {
      int lim = kc - t * 256; if (lim > 256) lim = 256;
      if (lim == 256) {
        #pragma unroll 8
        for (int u = 0; u < 256; ++u) rank += (tile[u] > q) ? 1 : 0;  // broadcast reads
      } else {
        for (int u = 0; u < lim; ++u) rank += (tile[u] > q) ? 1 : 0;
      }
    }
  }
  int h = ihp[0], w3 = iwp[0];
  double gd = fmin(640.0 / (double)h, 640.0 / (double)w3);
  float gain = (float)gd;
  float padx = (float)((640.0 - (double)w3 * gd) * 0.5);
  float pady = (float)((640.0 - (double)h * gd) * 0.5);
  float wf = (float)w3, hf = (float)h;
  if (havq) {
    if (rank < MAXDET) {
      unsigned int lo = (unsigned int)q;
      int aa = (int)((~(lo >> 16)) & 0xFFFFu);
      int cls = (int)(lo & 0xFFFFu);
      float score = __uint_as_float((unsigned int)(q >> 32));
      const float* row = pred + ((size_t)b * NN + aa) * ROWL;
      float cx = row[0], cy = row[1], wd = row[2], ht = row[3];
      float x1 = cx - wd / 2.0f, y1 = cy - ht / 2.0f;
      float x2 = cx + wd / 2.0f, y2 = cy + ht / 2.0f;
      x1 = rintf(fminf(fmaxf((x1 - padx) / gain, 0.0f), wf));
      y1 = rintf(fminf(fmaxf((y1 - pady) / gain, 0.0f), hf));
      x2 = rintf(fminf(fmaxf((x2 - padx) / gain, 0.0f), wf));
      y2 = rintf(fminf(fmaxf((y2 - pady) / gain, 0.0f), hf));
      float* o = out + ((size_t)b * MAXDET + rank) * 6;
      o[0] = x1; o[1] = y1; o[2] = x2; o[3] = y2;
      o[4] = score; o[5] = (float)cls;
    }
  } else if (i < MAXDET) {   // rows [kc, MAXDET): zero-fill
    float* o = out + ((size_t)b * MAXDET + i) * 6;
    o[0] = 0.0f; o[1] = 0.0f; o[2] = 0.0f; o[3] = 0.0f; o[4] = 0.0f; o[5] = 0.0f;
  }
}

extern "C" void kernel_launch(void* const* d_in, const int* in_sizes, int n_in,
                              void* d_out, int out_size, void* d_ws, size_t ws_size,
                              hipStream_t stream) {
  const float* pred = (const float*)d_in[0];
  const int* ih = (const int*)d_in[1];
  const int* iw = (const int*)d_in[2];
  float* out = (float*)d_out;
  char* ws = (char*)d_ws;

  unsigned int* pcnt = (unsigned int*)ws;
  unsigned int* cnt = (unsigned int*)(ws + OFF_CNT);
  unsigned int* kcnt = (unsigned int*)(ws + OFF_KCNT);
  unsigned long long* buckets = (unsigned long long*)(ws + OFF_BUCK);
  unsigned long long* kept = (unsigned long long*)(ws + OFF_KEPT);

  zero_kernel<<<ZERO_WORDS / 256, 256, 0, stream>>>((unsigned int*)ws);
  dim3 sgrid((NN + 255) / 256, BB);
  score_kernel<<<sgrid, 256, 0, stream>>>(pred, buckets, pcnt, cnt);
  dim3 cgrid(NC, BB);
  class_nms_kernel<<<cgrid, 64, 0, stream>>>(pred, buckets, pcnt, cnt, kept, kcnt);
  dim3 ogrid(KTOP / 256, BB);
  out_kernel<<<ogrid, 256, 0, stream>>>(pred, kept, kcnt, ih, iw, out);
}